// Round 8
// baseline (313.410 us; speedup 1.0000x reference)
//
#include <hip/hip_runtime.h>
#include <hip/hip_bf16.h>

#define T_ 1024
#define H_ 1024
#define I_ 512
#define IS_ 2048
#define E_ 16

typedef __attribute__((ext_vector_type(8))) short short8;
typedef __attribute__((ext_vector_type(4))) float f32x4;

__device__ __forceinline__ unsigned short f2bf(float f) {
  unsigned u = __builtin_bit_cast(unsigned, f);
  unsigned r = (u + 0x7fffu + ((u >> 16) & 1u)) >> 16;
  return (unsigned short)r;
}

// fp32 pair -> packed bf16x2 (RNE, identical rounding to f2bf)
__device__ __forceinline__ unsigned pk2(float lo, float hi) {
  return (unsigned)f2bf(lo) | ((unsigned)f2bf(hi) << 16);
}

// ---- router: one block per token; fused x->bf16 convert; logits/top-k/gate ----
__global__ __launch_bounds__(256) void k_router(
    const float* __restrict__ x, const float* __restrict__ wr,
    const float* __restrict__ wshg,
    unsigned short* __restrict__ xb, float* __restrict__ logits_out,
    int* __restrict__ top_i, float* __restrict__ top_w,
    float* __restrict__ gate_sig) {
  __shared__ float red[4][17];
  int t = blockIdx.x, tid = threadIdx.x;
  int h0 = tid << 2;
  float acc[17];
#pragma unroll
  for (int e = 0; e < 17; e++) acc[e] = 0.f;
  float4 xv = *(const float4*)(x + (long)t * H_ + h0);
  float4 wsh = *(const float4*)(wshg + h0);
  ushort4 xo;
  xo.x = f2bf(xv.x); xo.y = f2bf(xv.y); xo.z = f2bf(xv.z); xo.w = f2bf(xv.w);
  *(ushort4*)(xb + (long)t * H_ + h0) = xo;
  float xs[4] = {xv.x, xv.y, xv.z, xv.w};
  float ws[4] = {wsh.x, wsh.y, wsh.z, wsh.w};
#pragma unroll
  for (int j = 0; j < 4; j++) {
    const float4* w4 = (const float4*)(wr + (long)(h0 + j) * 16);
    float4 w0 = w4[0], w1 = w4[1], w2 = w4[2], w3 = w4[3];
    float xvj = xs[j];
    acc[0] += xvj * w0.x; acc[1] += xvj * w0.y; acc[2] += xvj * w0.z; acc[3] += xvj * w0.w;
    acc[4] += xvj * w1.x; acc[5] += xvj * w1.y; acc[6] += xvj * w1.z; acc[7] += xvj * w1.w;
    acc[8] += xvj * w2.x; acc[9] += xvj * w2.y; acc[10] += xvj * w2.z; acc[11] += xvj * w2.w;
    acc[12] += xvj * w3.x; acc[13] += xvj * w3.y; acc[14] += xvj * w3.z; acc[15] += xvj * w3.w;
    acc[16] += xvj * ws[j];
  }
#pragma unroll
  for (int off = 32; off >= 1; off >>= 1) {
#pragma unroll
    for (int e = 0; e < 17; e++) acc[e] += __shfl_xor(acc[e], off, 64);
  }
  int wid = tid >> 6, lane = tid & 63;
  if (lane == 0) {
#pragma unroll
    for (int e = 0; e < 17; e++) red[wid][e] = acc[e];
  }
  __syncthreads();
  if (tid == 0) {
    float a[17];
#pragma unroll
    for (int e = 0; e < 17; e++)
      a[e] = red[0][e] + red[1][e] + red[2][e] + red[3][e];
    float m = a[0];
#pragma unroll
    for (int e = 1; e < 16; e++) m = fmaxf(m, a[e]);
    float p[16], s = 0.f;
#pragma unroll
    for (int e = 0; e < 16; e++) { p[e] = expf(a[e] - m); s += p[e]; }
    float inv = 1.f / s;
#pragma unroll
    for (int e = 0; e < 16; e++) p[e] *= inv;
    int ti[4]; float tw[4]; float tsum = 0.f;
#pragma unroll
    for (int k = 0; k < 4; k++) {
      float best = -1.f; int bi = 0;
#pragma unroll
      for (int e = 0; e < 16; e++)
        if (p[e] > best) { best = p[e]; bi = e; }
      ti[k] = bi; tw[k] = best; tsum += best; p[bi] = -2.f;
    }
    float rn = 1.f / tsum;
#pragma unroll
    for (int e = 0; e < 16; e++) logits_out[(long)t * 16 + e] = a[e];
#pragma unroll
    for (int k = 0; k < 4; k++) {
      top_i[t * 4 + k] = ti[k];
      top_w[t * 4 + k] = tw[k] * rn;
    }
    gate_sig[t] = 1.f / (1.f + expf(-a[16]));
  }
}

// ------- build: histogram + prefix + scatter + compact tile worklists + wslot -------
// tile word: z[12+] | y[6:11] | x[0:5];  z==0 -> shared expert
__global__ __launch_bounds__(256) void k_build(
    const int* __restrict__ top_i, const float* __restrict__ top_w,
    int* __restrict__ counts, int* __restrict__ offsets,
    int* __restrict__ perm, float* __restrict__ wslot,
    int* __restrict__ gu_tiles, int* __restrict__ dn_tiles,
    int* __restrict__ ntl) {
  __shared__ int cnt[E_], cur[E_], mt[E_], pg[E_];
  int tid = threadIdx.x;
  if (tid < E_) cnt[tid] = 0;
  __syncthreads();
  for (int i = tid; i < T_ * 4; i += 256)
    atomicAdd(&cnt[top_i[i]], 1);
  __syncthreads();
  if (tid == 0) {
    int run = 0, trun = 0;
    for (int e = 0; e < E_; e++) {
      int c = cnt[e];
      counts[e] = c;
      offsets[e] = run;
      cur[e] = run;
      run += c;
      mt[e] = (c + 63) >> 6;
      pg[e] = trun;
      trun += mt[e];
    }
    ntl[0] = 512 + trun * 8;   // gu tiles
    ntl[1] = 256 + trun * 16;  // dn tiles
  }
  __syncthreads();
  for (int i = tid; i < T_ * 4; i += 256) {
    int e = top_i[i];
    int pos = atomicAdd(&cur[e], 1);
    perm[pos] = i >> 2;
    wslot[pos] = top_w[i];
  }
  for (int i = tid; i < 512; i += 256)
    gu_tiles[i] = ((i >> 5) << 6) | (i & 31);
  if (tid < 256)
    dn_tiles[tid] = ((tid >> 4) << 6) | (tid & 15);
  int trun = pg[E_ - 1] + mt[E_ - 1];
  for (int i = tid; i < trun * 8; i += 256) {
    int m = i >> 3, xx = i & 7;
    int e = 0;
    while (e < E_ - 1 && m >= pg[e] + mt[e]) e++;
    int y = m - pg[e];
    gu_tiles[512 + i] = ((e + 1) << 12) | (y << 6) | xx;
  }
  for (int i = tid; i < trun * 16; i += 256) {
    int m = i >> 4, xx = i & 15;
    int e = 0;
    while (e < E_ - 1 && m >= pg[e] + mt[e]) e++;
    int y = m - pg[e];
    dn_tiles[256 + i] = ((e + 1) << 12) | (y << 6) | xx;
  }
}

// ==== GEMMs: B consumed directly from NATIVE fp32 [K][N] weights.
// Reg-staged B: thread (n=tid&63, q=tid>>6) loads 8 fp32 of column ntile+n,
// rows 32kt+8q+i (each load = coalesced 256B across the wave), converts via
// pk2 (RNE), ds_write_b128 into LDS [64 rows][40 shorts] (pad-40: 80B row
// stride -> 16B-aligned rows, even 8-access/bank on write AND b128 read).
// Fragment semantics identical to the proven round-4 kernels:
// lane(quad,fr) holds k=8*quad..+7 of row fr. A reg-staged bf16 (1 dwordx4/thr).
// 2-deep reg ping-pong (static sets), ONE lgkm+barrier per K-step; vmcnt waits
// are compiler-derived (register dependencies).

// ---- gate/up GEMM: dual-N (g,u share A), silu fused, bf16 out ----
__global__ __launch_bounds__(256) void k_gemm_gu(
    const unsigned short* __restrict__ XB,
    const float* __restrict__ wsg, const float* __restrict__ wsu,
    const float* __restrict__ wg, const float* __restrict__ wu,
    unsigned short* __restrict__ HSB, unsigned short* __restrict__ HB,
    const int* __restrict__ counts, const int* __restrict__ offsets,
    const int* __restrict__ perm, const int* __restrict__ gu_tiles,
    const int* __restrict__ ntl) {
  __shared__ unsigned short lds[2][7680];  // As[64][40] | Bg +2560 | Bu +5120

  int tid = threadIdx.x, wid = tid >> 6, lane = tid & 63;
  int fr = lane & 15, quad = lane >> 4;
  int q8 = quad * 8;
  int wm = (wid >> 1) * 32, wn = (wid & 1) * 32;
  int ar = tid >> 2, aj = tid & 3;        // A staging: row, 8-k chunk
  int awoff = ar * 40 + aj * 8;
  int n_l = tid & 63, bq = tid >> 6;      // B staging: col, 8-k chunk (=wave)
  int bwoff = n_l * 40 + bq * 8;

  int n_tiles = ntl[0];
  for (int w = blockIdx.x; w < n_tiles; w += gridDim.x) {
    int twd = gu_tiles[w];
    int z = twd >> 12;
    int mtile = ((twd >> 6) & 63) * 64;
    int ntile = (twd & 63) * 64;
    int M, row_base, ldB, ldd;
    const float *BG, *BU;
    unsigned short* DST;
    const int* pp;
    if (z == 0) {
      M = T_; row_base = 0; BG = wsg; BU = wsu; ldB = IS_;
      DST = HSB; ldd = IS_; pp = nullptr;
    } else {
      int e = z - 1;
      M = counts[e];
      row_base = offsets[e];
      BG = wg + (long)e * H_ * I_;
      BU = wu + (long)e * H_ * I_;
      ldB = I_;
      DST = HB; ldd = I_; pp = perm;
    }

    int rm = mtile + ar;
    if (rm > M - 1) rm = M - 1;
    long arow = pp ? (long)pp[row_base + rm] : (long)(row_base + rm);
    const unsigned short* aptr = XB + arow * H_ + aj * 8;
    const float* bgp = BG + (long)bq * 8 * ldB + ntile + n_l;
    const float* bup = BU + (long)bq * 8 * ldB + ntile + n_l;

    f32x4 acc[2][2][2];
#pragma unroll
    for (int h = 0; h < 2; h++)
#pragma unroll
      for (int i = 0; i < 2; i++)
#pragma unroll
        for (int j = 0; j < 2; j++) acc[h][i][j] = (f32x4){0.f, 0.f, 0.f, 0.f};

    float vgA[8], vuA[8], vgB[8], vuB[8];
    short8 avA, avB;

    auto GLOAD = [&](float (&VG)[8], float (&VU)[8], short8& AV, int kt) {
      long ko = (long)kt * 32 * ldB;
#pragma unroll
      for (int i = 0; i < 8; i++) {
        VG[i] = bgp[ko + (long)i * ldB];
        VU[i] = bup[ko + (long)i * ldB];
      }
      AV = *(const short8*)(aptr + kt * 32);
    };
    auto GWRITE = [&](float (&VG)[8], float (&VU)[8], short8& AV, int s) {
      uint4 pg_, pu_;
      pg_.x = pk2(VG[0], VG[1]); pg_.y = pk2(VG[2], VG[3]);
      pg_.z = pk2(VG[4], VG[5]); pg_.w = pk2(VG[6], VG[7]);
      pu_.x = pk2(VU[0], VU[1]); pu_.y = pk2(VU[2], VU[3]);
      pu_.z = pk2(VU[4], VU[5]); pu_.w = pk2(VU[6], VU[7]);
      *(short8*)&lds[s][awoff] = AV;
      *(uint4*)&lds[s][2560 + bwoff] = pg_;
      *(uint4*)&lds[s][5120 + bwoff] = pu_;
    };
    auto GCOMP = [&](int s) {
      const unsigned short* L = &lds[s][0];
      short8 af0 = *(const short8*)&L[(wm + fr) * 40 + q8];
      short8 af1 = *(const short8*)&L[(wm + 16 + fr) * 40 + q8];
      short8 bg0 = *(const short8*)&L[2560 + (wn + fr) * 40 + q8];
      short8 bg1 = *(const short8*)&L[2560 + (wn + 16 + fr) * 40 + q8];
      short8 bu0 = *(const short8*)&L[5120 + (wn + fr) * 40 + q8];
      short8 bu1 = *(const short8*)&L[5120 + (wn + 16 + fr) * 40 + q8];
      acc[0][0][0] = __builtin_amdgcn_mfma_f32_16x16x32_bf16(af0, bg0, acc[0][0][0], 0, 0, 0);
      acc[0][0][1] = __builtin_amdgcn_mfma_f32_16x16x32_bf16(af0, bg1, acc[0][0][1], 0, 0, 0);
      acc[0][1][0] = __builtin_amdgcn_mfma_f32_16x16x32_bf16(af1, bg0, acc[0][1][0], 0, 0, 0);
      acc[0][1][1] = __builtin_amdgcn_mfma_f32_16x16x32_bf16(af1, bg1, acc[0][1][1], 0, 0, 0);
      acc[1][0][0] = __builtin_amdgcn_mfma_f32_16x16x32_bf16(af0, bu0, acc[1][0][0], 0, 0, 0);
      acc[1][0][1] = __builtin_amdgcn_mfma_f32_16x16x32_bf16(af0, bu1, acc[1][0][1], 0, 0, 0);
      acc[1][1][0] = __builtin_amdgcn_mfma_f32_16x16x32_bf16(af1, bu0, acc[1][1][0], 0, 0, 0);
      acc[1][1][1] = __builtin_amdgcn_mfma_f32_16x16x32_bf16(af1, bu1, acc[1][1][1], 0, 0, 0);
    };

    const int NK = H_ / 32;  // 32
    // prev tile's LDS reads done on all waves before re-staging
    asm volatile("s_waitcnt lgkmcnt(0)" ::: "memory");
    __builtin_amdgcn_sched_barrier(0);
    __builtin_amdgcn_s_barrier();
    __builtin_amdgcn_sched_barrier(0);
    GLOAD(vgA, vuA, avA, 0);
    GLOAD(vgB, vuB, avB, 1);
    GWRITE(vgA, vuA, avA, 0);
    asm volatile("s_waitcnt lgkmcnt(0)" ::: "memory");
    __builtin_amdgcn_sched_barrier(0);
    __builtin_amdgcn_s_barrier();
    __builtin_amdgcn_sched_barrier(0);
#pragma unroll 1
    for (int kt = 0; kt < NK; kt += 2) {
      // even step: compute lds[0] (tile kt); stage tile kt+1 -> lds[1]; load tile kt+2
      if (kt + 2 < NK) GLOAD(vgA, vuA, avA, kt + 2);
      GWRITE(vgB, vuB, avB, 1);
      GCOMP(0);
      asm volatile("s_waitcnt lgkmcnt(0)" ::: "memory");
      __builtin_amdgcn_sched_barrier(0);
      __builtin_amdgcn_s_barrier();
      __builtin_amdgcn_sched_barrier(0);
      // odd step: compute lds[1] (tile kt+1); stage tile kt+2 -> lds[0]; load tile kt+3
      if (kt + 3 < NK) GLOAD(vgB, vuB, avB, kt + 3);
      if (kt + 2 < NK) GWRITE(vgA, vuA, avA, 0);
      GCOMP(1);
      asm volatile("s_waitcnt lgkmcnt(0)" ::: "memory");
      __builtin_amdgcn_sched_barrier(0);
      __builtin_amdgcn_s_barrier();
      __builtin_amdgcn_sched_barrier(0);
    }

#pragma unroll
    for (int i = 0; i < 2; i++) {
      int m0 = mtile + wm + i * 16 + quad * 4;
#pragma unroll
      for (int j = 0; j < 2; j++) {
        int col = ntile + wn + j * 16 + fr;
#pragma unroll
        for (int r = 0; r < 4; r++) {
          int m = m0 + r;
          if (m < M) {
            float g = acc[0][i][j][r], u = acc[1][i][j][r];
            DST[(long)(row_base + m) * ldd + col] = f2bf(g / (1.f + expf(-g)) * u);
          }
        }
      }
    }
  }
}

// ---- down GEMM + fused combine epilogue (out pre-zeroed by harness) ----
__global__ __launch_bounds__(256) void k_gemm_dn(
    const unsigned short* __restrict__ HSB, const float* __restrict__ wsd,
    const unsigned short* __restrict__ HB, const float* __restrict__ wd,
    const int* __restrict__ counts, const int* __restrict__ offsets,
    const int* __restrict__ perm, const float* __restrict__ wslot,
    const float* __restrict__ gate_sig,
    const int* __restrict__ dn_tiles, const int* __restrict__ ntl,
    float* __restrict__ out) {
  __shared__ unsigned short lds[2][5120];  // As[64][40] | Bs +2560

  int tid = threadIdx.x, wid = tid >> 6, lane = tid & 63;
  int fr = lane & 15, quad = lane >> 4;
  int q8 = quad * 8;
  int wm = (wid >> 1) * 32, wn = (wid & 1) * 32;
  int ar = tid >> 2, aj = tid & 3;
  int awoff = ar * 40 + aj * 8;
  int n_l = tid & 63, bq = tid >> 6;
  int bwoff = n_l * 40 + bq * 8;

  int n_tiles = ntl[1];
  for (int w = blockIdx.x; w < n_tiles; w += gridDim.x) {
    int twd = dn_tiles[w];
    int z = twd >> 12;
    int mtile = ((twd >> 6) & 63) * 64;
    int ntile = (twd & 63) * 64;
    const unsigned short* A;
    const float* B;
    int K, M, rb;
    if (z == 0) {
      A = HSB; K = IS_; M = T_; rb = 0; B = wsd;
    } else {
      int e = z - 1;
      M = counts[e];
      rb = offsets[e];
      A = HB; K = I_; B = wd + (long)e * I_ * H_;
    }

    int rm = mtile + ar;
    if (rm > M - 1) rm = M - 1;
    const unsigned short* aptr = A + (long)(rb + rm) * K + aj * 8;
    const float* bp = B + (long)bq * 8 * H_ + ntile + n_l;

    f32x4 acc[2][2];
#pragma unroll
    for (int i = 0; i < 2; i++)
#pragma unroll
      for (int j = 0; j < 2; j++) acc[i][j] = (f32x4){0.f, 0.f, 0.f, 0.f};

    float vA[8], vB[8];
    short8 avA, avB;

    auto DLOAD = [&](float (&V)[8], short8& AV, int kt) {
      long ko = (long)kt * 32 * H_;
#pragma unroll
      for (int i = 0; i < 8; i++) V[i] = bp[ko + (long)i * H_];
      AV = *(const short8*)(aptr + kt * 32);
    };
    auto DWRITE = [&](float (&V)[8], short8& AV, int s) {
      uint4 pb_;
      pb_.x = pk2(V[0], V[1]); pb_.y = pk2(V[2], V[3]);
      pb_.z = pk2(V[4], V[5]); pb_.w = pk2(V[6], V[7]);
      *(short8*)&lds[s][awoff] = AV;
      *(uint4*)&lds[s][2560 + bwoff] = pb_;
    };
    auto DCOMP = [&](int s) {
      const unsigned short* L = &lds[s][0];
      short8 af0 = *(const short8*)&L[(wm + fr) * 40 + q8];
      short8 af1 = *(const short8*)&L[(wm + 16 + fr) * 40 + q8];
      short8 bf0 = *(const short8*)&L[2560 + (wn + fr) * 40 + q8];
      short8 bf1 = *(const short8*)&L[2560 + (wn + 16 + fr) * 40 + q8];
      acc[0][0] = __builtin_amdgcn_mfma_f32_16x16x32_bf16(af0, bf0, acc[0][0], 0, 0, 0);
      acc[0][1] = __builtin_amdgcn_mfma_f32_16x16x32_bf16(af0, bf1, acc[0][1], 0, 0, 0);
      acc[1][0] = __builtin_amdgcn_mfma_f32_16x16x32_bf16(af1, bf0, acc[1][0], 0, 0, 0);
      acc[1][1] = __builtin_amdgcn_mfma_f32_16x16x32_bf16(af1, bf1, acc[1][1], 0, 0, 0);
    };

    const int NK = K / 32;  // 16 or 64 (even)
    asm volatile("s_waitcnt lgkmcnt(0)" ::: "memory");
    __builtin_amdgcn_sched_barrier(0);
    __builtin_amdgcn_s_barrier();
    __builtin_amdgcn_sched_barrier(0);
    DLOAD(vA, avA, 0);
    DLOAD(vB, avB, 1);
    DWRITE(vA, avA, 0);
    asm volatile("s_waitcnt lgkmcnt(0)" ::: "memory");
    __builtin_amdgcn_sched_barrier(0);
    __builtin_amdgcn_s_barrier();
    __builtin_amdgcn_sched_barrier(0);
#pragma unroll 1
    for (int kt = 0; kt < NK; kt += 2) {
      if (kt + 2 < NK) DLOAD(vA, avA, kt + 2);
      DWRITE(vB, avB, 1);
      DCOMP(0);
      asm volatile("s_waitcnt lgkmcnt(0)" ::: "memory");
      __builtin_amdgcn_sched_barrier(0);
      __builtin_amdgcn_s_barrier();
      __builtin_amdgcn_sched_barrier(0);
      if (kt + 3 < NK) DLOAD(vB, avB, kt + 3);
      if (kt + 2 < NK) DWRITE(vA, avA, 0);
      DCOMP(1);
      asm volatile("s_waitcnt lgkmcnt(0)" ::: "memory");
      __builtin_amdgcn_sched_barrier(0);
      __builtin_amdgcn_s_barrier();
      __builtin_amdgcn_sched_barrier(0);
    }

    // fused-combine epilogue
#pragma unroll
    for (int i = 0; i < 2; i++) {
      int m0 = mtile + wm + i * 16 + quad * 4;
#pragma unroll
      for (int j = 0; j < 2; j++) {
        int col = ntile + wn + j * 16 + fr;
#pragma unroll
        for (int r = 0; r < 4; r++) {
          int m = m0 + r;
          if (m < M) {
            if (z == 0) {
              float gs = gate_sig[m];
              atomicAdd(&out[(long)m * H_ + col], gs * acc[i][j][r]);
            } else {
              int tkn = perm[rb + m];
              float wgt = wslot[rb + m];
              atomicAdd(&out[(long)tkn * H_ + col], wgt * acc[i][j][r]);
            }
          }
        }
      }
    }
  }
}

extern "C" void kernel_launch(void* const* d_in, const int* in_sizes, int n_in,
                              void* d_out, int out_size, void* d_ws, size_t ws_size,
                              hipStream_t stream) {
  const float* x    = (const float*)d_in[0];
  const float* wrt  = (const float*)d_in[1];
  const float* wg   = (const float*)d_in[2];
  const float* wu   = (const float*)d_in[3];
  const float* wd   = (const float*)d_in[4];
  const float* wsg  = (const float*)d_in[5];
  const float* wsu  = (const float*)d_in[6];
  const float* wsd  = (const float*)d_in[7];
  const float* wshg = (const float*)d_in[8];
  float* out = (float*)d_out;
  float* logits_out = out + (long)T_ * H_;

  char* ws = (char*)d_ws;
  size_t off = 0;
  auto take = [&](size_t bytes) -> void* {
    void* p = ws + off;
    off += (bytes + 255) & ~(size_t)255;
    return p;
  };

  unsigned short* XB    = (unsigned short*)take((size_t)T_ * H_ * 2);
  unsigned short* HSB   = (unsigned short*)take((size_t)T_ * IS_ * 2);
  unsigned short* HB    = (unsigned short*)take((size_t)4096 * I_ * 2);
  int*   counts   = (int*)take(64);
  int*   offsets  = (int*)take(64);
  int*   top_i    = (int*)take((size_t)T_ * 4 * 4);
  float* top_w    = (float*)take((size_t)T_ * 4 * 4);
  int*   perm     = (int*)take((size_t)4096 * 4);
  float* wslot    = (float*)take((size_t)4096 * 4);
  float* gate_sig = (float*)take((size_t)T_ * 4);
  int*   gu_tiles = (int*)take((size_t)2048 * 4);
  int*   dn_tiles = (int*)take((size_t)2048 * 4);
  int*   ntl      = (int*)take(64);

  // 4 launches: router -> build -> gu -> dn(+combine). No weight pre-pass.
  k_router<<<T_, 256, 0, stream>>>(x, wrt, wshg, XB, logits_out,
                                   top_i, top_w, gate_sig);
  k_build<<<1, 256, 0, stream>>>(top_i, top_w, counts, offsets, perm, wslot,
                                 gu_tiles, dn_tiles, ntl);
  k_gemm_gu<<<1024, 256, 0, stream>>>(XB, wsg, wsu, wg, wu, HSB, HB,
                                      counts, offsets, perm, gu_tiles, ntl);
  k_gemm_dn<<<1280, 256, 0, stream>>>(HSB, wsd, HB, wd,
                                      counts, offsets, perm, wslot, gate_sig,
                                      dn_tiles, ntl, out);
}

// Round 9
// 280.139 us; speedup vs baseline: 1.1188x; 1.1188x over previous
//
#include <hip/hip_runtime.h>
#include <hip/hip_bf16.h>

#define T_ 1024
#define H_ 1024
#define I_ 512
#define IS_ 2048
#define E_ 16

typedef __attribute__((ext_vector_type(8))) short short8;
typedef __attribute__((ext_vector_type(4))) float f32x4;

__device__ __forceinline__ unsigned short f2bf(float f) {
  unsigned u = __builtin_bit_cast(unsigned, f);
  unsigned r = (u + 0x7fffu + ((u >> 16) & 1u)) >> 16;
  return (unsigned short)r;
}

__device__ __forceinline__ void gload16(const void* g, void* l) {
  __builtin_amdgcn_global_load_lds(
      (const __attribute__((address_space(1))) unsigned int*)g,
      (__attribute__((address_space(3))) unsigned int*)l, 16, 0, 0);
}

// ---- column-strip transpose (round-4/6 proven, unchanged) ----
__device__ __forceinline__ void transpose_cstrip(
    const float* __restrict__ src, unsigned short* __restrict__ dst,
    int C, int Rf, int r_start, int n0, int nch) {
  __shared__ unsigned short tile[2][64 * 66];
  int tid = threadIdx.x;
  int c = (tid & 15) << 2;
  int r0 = (tid >> 4) << 2;
  int orr = tid >> 2;
  int ks = (tid & 3) << 4;
  const float* sp0 = src + (long)(r_start + r0) * C + n0 + c;
  unsigned short* dbase = dst + (long)(n0 + orr) * Rf + r_start + ks;

  float4 va[4], vb[4];
#pragma unroll
  for (int r = 0; r < 4; r++) va[r] = *(const float4*)(sp0 + (long)r * C);

  for (int t = 0; t < nch; t += 2) {
    {
      const float* sp = sp0 + (long)(t + 1) * 64 * C;
#pragma unroll
      for (int r = 0; r < 4; r++) vb[r] = *(const float4*)(sp + (long)r * C);
    }
    {
      unsigned short* tb = &tile[0][0];
      ushort4 w;
      w = (ushort4){f2bf(va[0].x), f2bf(va[1].x), f2bf(va[2].x), f2bf(va[3].x)};
      *(ushort4*)&tb[(c + 0) * 66 + r0] = w;
      w = (ushort4){f2bf(va[0].y), f2bf(va[1].y), f2bf(va[2].y), f2bf(va[3].y)};
      *(ushort4*)&tb[(c + 1) * 66 + r0] = w;
      w = (ushort4){f2bf(va[0].z), f2bf(va[1].z), f2bf(va[2].z), f2bf(va[3].z)};
      *(ushort4*)&tb[(c + 2) * 66 + r0] = w;
      w = (ushort4){f2bf(va[0].w), f2bf(va[1].w), f2bf(va[2].w), f2bf(va[3].w)};
      *(ushort4*)&tb[(c + 3) * 66 + r0] = w;
      asm volatile("s_waitcnt lgkmcnt(0)" ::: "memory");
      __builtin_amdgcn_sched_barrier(0);
      __builtin_amdgcn_s_barrier();
      __builtin_amdgcn_sched_barrier(0);
      uint4 o0 = *(const uint4*)&tb[orr * 66 + ks];
      uint4 o1 = *(const uint4*)&tb[orr * 66 + ks + 8];
      unsigned short* d = dbase + (long)t * 64;
      *(uint4*)d = o0;
      *(uint4*)(d + 8) = o1;
    }
    if (t + 2 < nch) {
      const float* sp = sp0 + (long)(t + 2) * 64 * C;
#pragma unroll
      for (int r = 0; r < 4; r++) va[r] = *(const float4*)(sp + (long)r * C);
    }
    {
      unsigned short* tb = &tile[1][0];
      ushort4 w;
      w = (ushort4){f2bf(vb[0].x), f2bf(vb[1].x), f2bf(vb[2].x), f2bf(vb[3].x)};
      *(ushort4*)&tb[(c + 0) * 66 + r0] = w;
      w = (ushort4){f2bf(vb[0].y), f2bf(vb[1].y), f2bf(vb[2].y), f2bf(vb[3].y)};
      *(ushort4*)&tb[(c + 1) * 66 + r0] = w;
      w = (ushort4){f2bf(vb[0].z), f2bf(vb[1].z), f2bf(vb[2].z), f2bf(vb[3].z)};
      *(ushort4*)&tb[(c + 2) * 66 + r0] = w;
      w = (ushort4){f2bf(vb[0].w), f2bf(vb[1].w), f2bf(vb[2].w), f2bf(vb[3].w)};
      *(ushort4*)&tb[(c + 3) * 66 + r0] = w;
      asm volatile("s_waitcnt lgkmcnt(0)" ::: "memory");
      __builtin_amdgcn_sched_barrier(0);
      __builtin_amdgcn_s_barrier();
      __builtin_amdgcn_sched_barrier(0);
      uint4 o0 = *(const uint4*)&tb[orr * 66 + ks];
      uint4 o1 = *(const uint4*)&tb[orr * 66 + ks + 8];
      unsigned short* d = dbase + (long)(t + 1) * 64;
      *(uint4*)d = o0;
      *(uint4*)(d + 8) = o1;
    }
  }
}

// ---- router (round-6 proven, unchanged) ----
__global__ __launch_bounds__(256) void k_router(
    const float* __restrict__ x, const float* __restrict__ wr,
    const float* __restrict__ wshg,
    unsigned short* __restrict__ xb, float* __restrict__ logits_out,
    int* __restrict__ top_i, float* __restrict__ top_w,
    float* __restrict__ gate_sig) {
  __shared__ float red[4][17];
  int t = blockIdx.x, tid = threadIdx.x;
  int h0 = tid << 2;
  float acc[17];
#pragma unroll
  for (int e = 0; e < 17; e++) acc[e] = 0.f;
  float4 xv = *(const float4*)(x + (long)t * H_ + h0);
  float4 wsh = *(const float4*)(wshg + h0);
  ushort4 xo;
  xo.x = f2bf(xv.x); xo.y = f2bf(xv.y); xo.z = f2bf(xv.z); xo.w = f2bf(xv.w);
  *(ushort4*)(xb + (long)t * H_ + h0) = xo;
  float xs[4] = {xv.x, xv.y, xv.z, xv.w};
  float ws[4] = {wsh.x, wsh.y, wsh.z, wsh.w};
#pragma unroll
  for (int j = 0; j < 4; j++) {
    const float4* w4 = (const float4*)(wr + (long)(h0 + j) * 16);
    float4 w0 = w4[0], w1 = w4[1], w2 = w4[2], w3 = w4[3];
    float xvj = xs[j];
    acc[0] += xvj * w0.x; acc[1] += xvj * w0.y; acc[2] += xvj * w0.z; acc[3] += xvj * w0.w;
    acc[4] += xvj * w1.x; acc[5] += xvj * w1.y; acc[6] += xvj * w1.z; acc[7] += xvj * w1.w;
    acc[8] += xvj * w2.x; acc[9] += xvj * w2.y; acc[10] += xvj * w2.z; acc[11] += xvj * w2.w;
    acc[12] += xvj * w3.x; acc[13] += xvj * w3.y; acc[14] += xvj * w3.z; acc[15] += xvj * w3.w;
    acc[16] += xvj * ws[j];
  }
#pragma unroll
  for (int off = 32; off >= 1; off >>= 1) {
#pragma unroll
    for (int e = 0; e < 17; e++) acc[e] += __shfl_xor(acc[e], off, 64);
  }
  int wid = tid >> 6, lane = tid & 63;
  if (lane == 0) {
#pragma unroll
    for (int e = 0; e < 17; e++) red[wid][e] = acc[e];
  }
  __syncthreads();
  if (tid == 0) {
    float a[17];
#pragma unroll
    for (int e = 0; e < 17; e++)
      a[e] = red[0][e] + red[1][e] + red[2][e] + red[3][e];
    float m = a[0];
#pragma unroll
    for (int e = 1; e < 16; e++) m = fmaxf(m, a[e]);
    float p[16], s = 0.f;
#pragma unroll
    for (int e = 0; e < 16; e++) { p[e] = expf(a[e] - m); s += p[e]; }
    float inv = 1.f / s;
#pragma unroll
    for (int e = 0; e < 16; e++) p[e] *= inv;
    int ti[4]; float tw[4]; float tsum = 0.f;
#pragma unroll
    for (int k = 0; k < 4; k++) {
      float best = -1.f; int bi = 0;
#pragma unroll
      for (int e = 0; e < 16; e++)
        if (p[e] > best) { best = p[e]; bi = e; }
      ti[k] = bi; tw[k] = best; tsum += best; p[bi] = -2.f;
    }
    float rn = 1.f / tsum;
#pragma unroll
    for (int e = 0; e < 16; e++) logits_out[(long)t * 16 + e] = a[e];
#pragma unroll
    for (int k = 0; k < 4; k++) {
      top_i[t * 4 + k] = ti[k];
      top_w[t * 4 + k] = tw[k] * rn;
    }
    gate_sig[t] = 1.f / (1.f + expf(-a[16]));
  }
}

// ---- wt+build: blocks 0..959 transposes (proven); block 960 build.
//      Worklists now use 128-row mtiles. ----
__global__ __launch_bounds__(256) void k_wtb(
    const float* __restrict__ wg, const float* __restrict__ wu,
    const float* __restrict__ wd, const float* __restrict__ wsg,
    const float* __restrict__ wsu, const float* __restrict__ wsd,
    unsigned short* __restrict__ WGUT, unsigned short* __restrict__ WDT,
    unsigned short* __restrict__ WSGUT, unsigned short* __restrict__ WSDT,
    const int* __restrict__ top_i, const float* __restrict__ top_w,
    int* __restrict__ counts, int* __restrict__ offsets,
    int* __restrict__ perm, float* __restrict__ wslot,
    int* __restrict__ gu_tiles, int* __restrict__ dn_tiles,
    int* __restrict__ ntl) {
  int id = blockIdx.x;
  if (id < 960) {
    const float* src; unsigned short* dst; int C, Rf, r0s, n0, nch;
    if (id < 64) {
      int s = id >> 2, q = id & 3;
      src = wsd; dst = WSDT; C = H_; Rf = IS_;
      n0 = s * 64; r0s = q * 512; nch = 8;
    } else if (id < 128) {
      int l = id - 64, s = l >> 1, h = l & 1;
      src = wsg; dst = WSGUT; C = IS_; Rf = H_;
      n0 = s * 64; r0s = h * 512; nch = 8;
    } else if (id < 192) {
      int l = id - 128, s = l >> 1, h = l & 1;
      src = wsu; dst = WSGUT + (long)IS_ * H_; C = IS_; Rf = H_;
      n0 = s * 64; r0s = h * 512; nch = 8;
    } else if (id < 448) {
      int l = id - 192, e = l >> 4, s = (l >> 1) & 7, h = l & 1;
      src = wg + (long)e * H_ * I_; dst = WGUT + (long)e * 2 * I_ * H_;
      C = I_; Rf = H_; n0 = s * 64; r0s = h * 512; nch = 8;
    } else if (id < 704) {
      int l = id - 448, e = l >> 4, s = (l >> 1) & 7, h = l & 1;
      src = wu + (long)e * H_ * I_;
      dst = WGUT + (long)e * 2 * I_ * H_ + (long)I_ * H_;
      C = I_; Rf = H_; n0 = s * 64; r0s = h * 512; nch = 8;
    } else {
      int l = id - 704, e = l >> 4, s = l & 15;
      src = wd + (long)e * I_ * H_; dst = WDT + (long)e * H_ * I_;
      C = H_; Rf = I_; n0 = s * 64; r0s = 0; nch = 8;
    }
    transpose_cstrip(src, dst, C, Rf, r0s, n0, nch);
    return;
  }
  // ---- build (block 960); mtiles are 128 rows ----
  __shared__ int cnt[E_], cur[E_], mt[E_], pg[E_];
  int tid = threadIdx.x;
  if (tid < E_) cnt[tid] = 0;
  __syncthreads();
  for (int i = tid; i < T_ * 4; i += 256)
    atomicAdd(&cnt[top_i[i]], 1);
  __syncthreads();
  if (tid == 0) {
    int run = 0, trun = 0;
    for (int e = 0; e < E_; e++) {
      int c = cnt[e];
      counts[e] = c;
      offsets[e] = run;
      cur[e] = run;
      run += c;
      mt[e] = (c + 127) >> 7;
      pg[e] = trun;
      trun += mt[e];
    }
    ntl[0] = 256 + trun * 8;   // gu: shared 8x32 + experts mt*8
    ntl[1] = 128 + trun * 16;  // dn: shared 8x16 + experts mt*16
  }
  __syncthreads();
  for (int i = tid; i < T_ * 4; i += 256) {
    int e = top_i[i];
    int pos = atomicAdd(&cur[e], 1);
    perm[pos] = i >> 2;
    wslot[pos] = top_w[i];
  }
  // shared tiles first (dn shared = long K=2048 -> LPT order)
  if (tid < 256)
    gu_tiles[tid] = ((tid >> 5) << 6) | (tid & 31);
  if (tid < 128)
    dn_tiles[tid] = ((tid >> 4) << 6) | (tid & 15);
  int trun = pg[E_ - 1] + mt[E_ - 1];
  for (int i = tid; i < trun * 8; i += 256) {
    int m = i >> 3, xx = i & 7;
    int e = 0;
    while (e < E_ - 1 && m >= pg[e] + mt[e]) e++;
    int y = m - pg[e];
    gu_tiles[256 + i] = ((e + 1) << 12) | (y << 6) | xx;
  }
  for (int i = tid; i < trun * 16; i += 256) {
    int m = i >> 4, xx = i & 15;
    int e = 0;
    while (e < E_ - 1 && m >= pg[e] + mt[e]) e++;
    int y = m - pg[e];
    dn_tiles[128 + i] = ((e + 1) << 12) | (y << 6) | xx;
  }
}

// ---- gate/up GEMM: 128Mx64N tile, dual-N (g,u share A), depth-3 pipeline,
//      counted vmcnt(4), worklist grid, silu fused, bf16 out.
//      Per wave per K-step: 16 MFMA (2x density of the 64x64 version). ----
__global__ __launch_bounds__(256) void k_gemm_gu(
    const unsigned short* __restrict__ XB,
    const unsigned short* __restrict__ WSGUT, const unsigned short* __restrict__ WGUT,
    unsigned short* __restrict__ HSB, unsigned short* __restrict__ HB,
    const int* __restrict__ counts, const int* __restrict__ offsets,
    const int* __restrict__ perm, const int* __restrict__ gu_tiles,
    const int* __restrict__ ntl) {
  __shared__ unsigned short lds[3][8192];  // As[128][32] | Bg +4096 | Bu +6144

  int tid = threadIdx.x, wid = tid >> 6, lane = tid & 63;
  int sub = lane >> 2;
  int ksw = ((lane & 3) ^ ((sub >> 1) & 3)) << 3;
  int fr = lane & 15, quad = lane >> 4;
  int fslot = (quad ^ ((fr >> 1) & 3)) << 3;

  int n_tiles = ntl[0];
  for (int w = blockIdx.x; w < n_tiles; w += gridDim.x) {
    int twd = gu_tiles[w];
    int z = twd >> 12;
    int mtile = ((twd >> 6) & 63) * 128;
    int ntile = (twd & 63) * 64;
    int M, row_base, uoff, ldd;
    const unsigned short* B0;
    unsigned short* DST;
    const int* pp;
    if (z == 0) {
      M = T_; row_base = 0; B0 = WSGUT; uoff = IS_;
      DST = HSB; ldd = IS_; pp = nullptr;
    } else {
      int e = z - 1;
      M = counts[e];
      row_base = offsets[e];
      B0 = WGUT + (long)e * 2 * I_ * H_;
      uoff = I_;
      DST = HB; ldd = I_; pp = perm;
    }

    int r0 = mtile + wid * 32 + sub;
    int r1 = r0 + 16;
    if (r0 > M - 1) r0 = M - 1;
    if (r1 > M - 1) r1 = M - 1;
    long a0 = pp ? (long)pp[row_base + r0] : (long)(row_base + r0);
    long a1 = pp ? (long)pp[row_base + r1] : (long)(row_base + r1);
    const unsigned short* aptr0 = XB + a0 * H_ + ksw;
    const unsigned short* aptr1 = XB + a1 * H_ + ksw;
    int rbn = ntile + wid * 16 + sub;
    const unsigned short* bgptr = B0 + (long)rbn * H_ + ksw;
    const unsigned short* buptr = B0 + (long)(rbn + uoff) * H_ + ksw;

    f32x4 acc[2][2][4];
#pragma unroll
    for (int h = 0; h < 2; h++)
#pragma unroll
      for (int i = 0; i < 2; i++)
#pragma unroll
        for (int j = 0; j < 4; j++) acc[h][i][j] = (f32x4){0.f, 0.f, 0.f, 0.f};

    auto STAGE = [&](int slot, int kt) {
      int ko = kt * 32;
      unsigned short* base = &lds[slot][0];
      gload16(aptr0 + ko, base + wid * 1024);
      gload16(aptr1 + ko, base + wid * 1024 + 512);
      gload16(bgptr + ko, base + 4096 + wid * 512);
      gload16(buptr + ko, base + 6144 + wid * 512);
    };

    const int NK = H_ / 32;
    asm volatile("s_waitcnt lgkmcnt(0)" ::: "memory");
    __builtin_amdgcn_s_barrier();
    __builtin_amdgcn_sched_barrier(0);
    STAGE(0, 0);
    STAGE(1, 1);
    int cur = 0, stg = 2;
    for (int kt = 0; kt < NK; kt++) {
      if (kt + 1 < NK) asm volatile("s_waitcnt vmcnt(4)" ::: "memory");
      else             asm volatile("s_waitcnt vmcnt(0)" ::: "memory");
      __builtin_amdgcn_s_barrier();
      __builtin_amdgcn_sched_barrier(0);
      if (kt + 2 < NK) STAGE(stg, kt + 2);
      __builtin_amdgcn_sched_barrier(0);
      const unsigned short* As = &lds[cur][0];
      const unsigned short* Bg = &lds[cur][4096];
      const unsigned short* Bu = &lds[cur][6144];
      short8 af[2], bg[4], bu[4];
#pragma unroll
      for (int i = 0; i < 2; i++)
        af[i] = *(const short8*)(&As[(wid * 32 + i * 16 + fr) * 32 + fslot]);
#pragma unroll
      for (int j = 0; j < 4; j++) {
        bg[j] = *(const short8*)(&Bg[(j * 16 + fr) * 32 + fslot]);
        bu[j] = *(const short8*)(&Bu[(j * 16 + fr) * 32 + fslot]);
      }
#pragma unroll
      for (int i = 0; i < 2; i++)
#pragma unroll
        for (int j = 0; j < 4; j++) {
          acc[0][i][j] = __builtin_amdgcn_mfma_f32_16x16x32_bf16(af[i], bg[j], acc[0][i][j], 0, 0, 0);
          acc[1][i][j] = __builtin_amdgcn_mfma_f32_16x16x32_bf16(af[i], bu[j], acc[1][i][j], 0, 0, 0);
        }
      asm volatile("s_waitcnt lgkmcnt(0)" ::: "memory");
      __builtin_amdgcn_sched_barrier(0);
      cur = (cur == 2) ? 0 : cur + 1;
      stg = (stg == 2) ? 0 : stg + 1;
    }

#pragma unroll
    for (int i = 0; i < 2; i++) {
      int m0 = mtile + wid * 32 + i * 16 + quad * 4;
#pragma unroll
      for (int j = 0; j < 4; j++) {
        int col = ntile + j * 16 + fr;
#pragma unroll
        for (int r = 0; r < 4; r++) {
          int m = m0 + r;
          if (m < M) {
            float g = acc[0][i][j][r], u = acc[1][i][j][r];
            DST[(long)(row_base + m) * ldd + col] = f2bf(g / (1.f + expf(-g)) * u);
          }
        }
      }
    }
  }
}

// ---- down GEMM: 128Mx64N tile, depth-3, vmcnt(3), fused atomic combine ----
__global__ __launch_bounds__(256) void k_gemm_dn(
    const unsigned short* __restrict__ HSB, const unsigned short* __restrict__ WSDT,
    const unsigned short* __restrict__ HB, const unsigned short* __restrict__ WDT,
    const int* __restrict__ counts, const int* __restrict__ offsets,
    const int* __restrict__ perm, const float* __restrict__ wslot,
    const float* __restrict__ gate_sig,
    const int* __restrict__ dn_tiles, const int* __restrict__ ntl,
    float* __restrict__ out) {
  __shared__ unsigned short lds[3][6144];  // As[128][32] | Bs +4096

  int tid = threadIdx.x, wid = tid >> 6, lane = tid & 63;
  int sub = lane >> 2;
  int ksw = ((lane & 3) ^ ((sub >> 1) & 3)) << 3;
  int fr = lane & 15, quad = lane >> 4;
  int fslot = (quad ^ ((fr >> 1) & 3)) << 3;

  int n_tiles = ntl[1];
  for (int w = blockIdx.x; w < n_tiles; w += gridDim.x) {
    int twd = dn_tiles[w];
    int z = twd >> 12;
    int mtile = ((twd >> 6) & 63) * 128;
    int ntile = (twd & 63) * 64;
    const unsigned short *A, *B;
    int K, M, rb;
    if (z == 0) {
      A = HSB; K = IS_; M = T_; rb = 0; B = WSDT;
    } else {
      int e = z - 1;
      M = counts[e];
      rb = offsets[e];
      A = HB; K = I_; B = WDT + (long)e * H_ * I_;
    }

    int r0 = mtile + wid * 32 + sub;
    int r1 = r0 + 16;
    if (r0 > M - 1) r0 = M - 1;
    if (r1 > M - 1) r1 = M - 1;
    const unsigned short* aptr0 = A + (long)(rb + r0) * K + ksw;
    const unsigned short* aptr1 = A + (long)(rb + r1) * K + ksw;
    int rbn = ntile + wid * 16 + sub;
    const unsigned short* bptr = B + (long)rbn * K + ksw;

    f32x4 acc[2][4];
#pragma unroll
    for (int i = 0; i < 2; i++)
#pragma unroll
      for (int j = 0; j < 4; j++) acc[i][j] = (f32x4){0.f, 0.f, 0.f, 0.f};

    auto STAGE = [&](int slot, int kt) {
      int ko = kt * 32;
      unsigned short* base = &lds[slot][0];
      gload16(aptr0 + ko, base + wid * 1024);
      gload16(aptr1 + ko, base + wid * 1024 + 512);
      gload16(bptr + ko, base + 4096 + wid * 512);
    };

    const int NK = K / 32;
    asm volatile("s_waitcnt lgkmcnt(0)" ::: "memory");
    __builtin_amdgcn_s_barrier();
    __builtin_amdgcn_sched_barrier(0);
    STAGE(0, 0);
    STAGE(1, 1);
    int cur = 0, stg = 2;
    for (int kt = 0; kt < NK; kt++) {
      if (kt + 1 < NK) asm volatile("s_waitcnt vmcnt(3)" ::: "memory");
      else             asm volatile("s_waitcnt vmcnt(0)" ::: "memory");
      __builtin_amdgcn_s_barrier();
      __builtin_amdgcn_sched_barrier(0);
      if (kt + 2 < NK) STAGE(stg, kt + 2);
      __builtin_amdgcn_sched_barrier(0);
      const unsigned short* As = &lds[cur][0];
      const unsigned short* Bs = &lds[cur][4096];
      short8 af[2], bf[4];
#pragma unroll
      for (int i = 0; i < 2; i++)
        af[i] = *(const short8*)(&As[(wid * 32 + i * 16 + fr) * 32 + fslot]);
#pragma unroll
      for (int j = 0; j < 4; j++)
        bf[j] = *(const short8*)(&Bs[(j * 16 + fr) * 32 + fslot]);
#pragma unroll
      for (int i = 0; i < 2; i++)
#pragma unroll
        for (int j = 0; j < 4; j++)
          acc[i][j] = __builtin_amdgcn_mfma_f32_16x16x32_bf16(af[i], bf[j], acc[i][j], 0, 0, 0);
      asm volatile("s_waitcnt lgkmcnt(0)" ::: "memory");
      __builtin_amdgcn_sched_barrier(0);
      cur = (cur == 2) ? 0 : cur + 1;
      stg = (stg == 2) ? 0 : stg + 1;
    }

    // fused-combine epilogue (out pre-zeroed by harness each iteration)
#pragma unroll
    for (int i = 0; i < 2; i++) {
      int m0 = mtile + wid * 32 + i * 16 + quad * 4;
#pragma unroll
      for (int j = 0; j < 4; j++) {
        int col = ntile + j * 16 + fr;
#pragma unroll
        for (int r = 0; r < 4; r++) {
          int m = m0 + r;
          if (m < M) {
            if (z == 0) {
              float gs = gate_sig[m];
              atomicAdd(&out[(long)m * H_ + col], gs * acc[i][j][r]);
            } else {
              int tkn = perm[rb + m];
              float wgt = wslot[rb + m];
              atomicAdd(&out[(long)tkn * H_ + col], wgt * acc[i][j][r]);
            }
          }
        }
      }
    }
  }
}

extern "C" void kernel_launch(void* const* d_in, const int* in_sizes, int n_in,
                              void* d_out, int out_size, void* d_ws, size_t ws_size,
                              hipStream_t stream) {
  const float* x    = (const float*)d_in[0];
  const float* wrt  = (const float*)d_in[1];
  const float* wg   = (const float*)d_in[2];
  const float* wu   = (const float*)d_in[3];
  const float* wd   = (const float*)d_in[4];
  const float* wsg  = (const float*)d_in[5];
  const float* wsu  = (const float*)d_in[6];
  const float* wsd  = (const float*)d_in[7];
  const float* wshg = (const float*)d_in[8];
  float* out = (float*)d_out;
  float* logits_out = out + (long)T_ * H_;

  char* ws = (char*)d_ws;
  size_t off = 0;
  auto take = [&](size_t bytes) -> void* {
    void* p = ws + off;
    off += (bytes + 255) & ~(size_t)255;
    return p;
  };

  unsigned short* XB    = (unsigned short*)take((size_t)T_ * H_ * 2);
  unsigned short* WGUT  = (unsigned short*)take((size_t)E_ * 2 * I_ * H_ * 2);  // [e][g|u rows][h]
  unsigned short* WDT   = (unsigned short*)take((size_t)E_ * H_ * I_ * 2);      // [e][n=H][k=I]
  unsigned short* WSGUT = (unsigned short*)take((size_t)2 * IS_ * H_ * 2);      // [g|u rows][h]
  unsigned short* WSDT  = (unsigned short*)take((size_t)H_ * IS_ * 2);          // [n=H][k=IS]
  unsigned short* HSB   = (unsigned short*)take((size_t)T_ * IS_ * 2);
  unsigned short* HB    = (unsigned short*)take((size_t)4096 * I_ * 2);
  int*   counts   = (int*)take(64);
  int*   offsets  = (int*)take(64);
  int*   top_i    = (int*)take((size_t)T_ * 4 * 4);
  float* top_w    = (float*)take((size_t)T_ * 4 * 4);
  int*   perm     = (int*)take((size_t)4096 * 4);
  float* wslot    = (float*)take((size_t)4096 * 4);
  float* gate_sig = (float*)take((size_t)T_ * 4);
  int*   gu_tiles = (int*)take((size_t)2048 * 4);
  int*   dn_tiles = (int*)take((size_t)2048 * 4);
  int*   ntl      = (int*)take(64);

  // 4 launches: router -> wt+build -> gu -> dn(+combine fused)
  k_router<<<T_, 256, 0, stream>>>(x, wrt, wshg, XB, logits_out,
                                   top_i, top_w, gate_sig);
  k_wtb<<<961, 256, 0, stream>>>(wg, wu, wd, wsg, wsu, wsd,
                                 WGUT, WDT, WSGUT, WSDT,
                                 top_i, top_w, counts, offsets, perm, wslot,
                                 gu_tiles, dn_tiles, ntl);
  k_gemm_gu<<<640, 256, 0, stream>>>(XB, WSGUT, WGUT, HSB, HB,
                                     counts, offsets, perm, gu_tiles, ntl);
  k_gemm_dn<<<640, 256, 0, stream>>>(HSB, WSDT, HB, WDT,
                                     counts, offsets, perm, wslot, gate_sig,
                                     dn_tiles, ntl, out);
}